// Round 4
// baseline (174.377 us; speedup 1.0000x reference)
//
#include <hip/hip_runtime.h>
#include <hip/hip_bf16.h>

#define DIM 512
#define SEQ 2048
#define BATCH 4
#define NHEADS 8
#define DH 64
#define NROWS (BATCH * SEQ)
#define LN_EPS 1e-5f

typedef __hip_bfloat16 bf16;
typedef __attribute__((ext_vector_type(8))) short short8;
typedef __attribute__((ext_vector_type(4))) float f32x4;

#define MFMA16(a, b, c) __builtin_amdgcn_mfma_f32_16x16x32_bf16((a), (b), (c), 0, 0, 0)

#if __has_builtin(__builtin_amdgcn_exp2f)
#define EXP2(x) __builtin_amdgcn_exp2f(x)
#else
#define EXP2(x) exp2f(x)
#endif

#if defined(__has_builtin)
#if __has_builtin(__builtin_amdgcn_global_load_lds)
#define HAS_GLDS 1
#endif
#endif

// async global->LDS, 16B per lane; LDS dest = wave-uniform base + lane*16
__device__ __forceinline__ void glds16(const bf16* g, bf16* l) {
#ifdef HAS_GLDS
  __builtin_amdgcn_global_load_lds((const __attribute__((address_space(1))) void*)g,
                                   (__attribute__((address_space(3))) void*)l, 16, 0, 0);
#else
  *reinterpret_cast<uint4*>(l) = *reinterpret_cast<const uint4*>(g);
#endif
}

__device__ __forceinline__ void store_bf16x4(bf16* p, float a, float b, float c, float d) {
  bf16 tmp[4] = {__float2bfloat16(a), __float2bfloat16(b), __float2bfloat16(c),
                 __float2bfloat16(d)};
  *reinterpret_cast<ushort4*>(p) = *reinterpret_cast<const ushort4*>(tmp);
}

#define B2F(us) __uint_as_float(((unsigned)(us)) << 16)

// raw barrier (no compiler-forced vmcnt(0) drain) + manual vm waits (m201 pattern)
#define BARRIER() asm volatile("s_barrier" ::: "memory")
#define WAITVM0() asm volatile("s_waitcnt vmcnt(0)" ::: "memory")

// scale * log2(e), folded into Wq so attention's softmax is a bare v_exp_f32
#define Q_SCALE_LOG2E 0.06375872f

// -------- Fused setup: LayerNorm wave-per-row (blocks [0,NROWS/4)) + weight transposes --------
__global__ void setup_kernel(const float* __restrict__ x, const float* __restrict__ gamma,
                             const float* __restrict__ beta, bf16* __restrict__ xn,
                             const float* __restrict__ Wq, const float* __restrict__ Wk,
                             const float* __restrict__ Wv, const float* __restrict__ Wo,
                             bf16* __restrict__ Wt) {
  const int t = threadIdx.x;
  if (blockIdx.x < NROWS / 4) {
    // ---- LayerNorm: one wave per row, no barriers; lane holds 8 elems (2x float4) ----
    const int row = blockIdx.x * 4 + (t >> 6);
    const int l = t & 63;
    const float4* xr = reinterpret_cast<const float4*>(x + (size_t)row * DIM);
    const float4 v0 = xr[l * 2];
    const float4 v1 = xr[l * 2 + 1];
    float s = (v0.x + v0.y + v0.z + v0.w) + (v1.x + v1.y + v1.z + v1.w);
    float ss = v0.x * v0.x + v0.y * v0.y + v0.z * v0.z + v0.w * v0.w + v1.x * v1.x +
               v1.y * v1.y + v1.z * v1.z + v1.w * v1.w;
#pragma unroll
    for (int off = 1; off < 64; off <<= 1) {
      s += __shfl_xor(s, off);
      ss += __shfl_xor(ss, off);
    }
    const float mu = s * (1.0f / DIM);
    const float rs = rsqrtf(ss * (1.0f / DIM) - mu * mu + LN_EPS);
    const float4 g0 = reinterpret_cast<const float4*>(gamma)[l * 2];
    const float4 g1 = reinterpret_cast<const float4*>(gamma)[l * 2 + 1];
    const float4 b0 = reinterpret_cast<const float4*>(beta)[l * 2];
    const float4 b1 = reinterpret_cast<const float4*>(beta)[l * 2 + 1];
    bf16* o = xn + (size_t)row * DIM + l * 8;
    store_bf16x4(o, (v0.x - mu) * rs * g0.x + b0.x, (v0.y - mu) * rs * g0.y + b0.y,
                 (v0.z - mu) * rs * g0.z + b0.z, (v0.w - mu) * rs * g0.w + b0.w);
    store_bf16x4(o + 4, (v1.x - mu) * rs * g1.x + b1.x, (v1.y - mu) * rs * g1.y + b1.y,
                 (v1.z - mu) * rs * g1.z + b1.z, (v1.w - mu) * rs * g1.w + b1.w);
  } else {
    // ---- weight transpose + cast + scale: W[K][N] fp32 -> Wt[N][K] bf16 ----
    __shared__ float tile[32][33];
    const int idx = blockIdx.x - NROWS / 4;
    const int bx = idx & 15, by = (idx >> 4) & 15, z = idx >> 8;
    const float* __restrict__ W = (z == 0) ? Wq : (z == 1) ? Wk : (z == 2) ? Wv : Wo;
    const float scale = (z == 0) ? Q_SCALE_LOG2E : 1.0f;
    bf16* __restrict__ dst = Wt + (size_t)z * DIM * DIM;
    const int tx = t & 31, ty = t >> 5;  // 32 x 8
#pragma unroll
    for (int i = 0; i < 32; i += 8)
      tile[ty + i][tx] = W[(size_t)(by * 32 + ty + i) * DIM + bx * 32 + tx];
    __syncthreads();
#pragma unroll
    for (int i = 0; i < 32; i += 8)
      dst[(size_t)(bx * 32 + ty + i) * DIM + by * 32 + tx] =
          __float2bfloat16(tile[tx][ty + i] * scale);
  }
}

// ------ Fused QKV GEMM: C[M,1536] = A[M,512] @ Wt[1536,512]^T, 128x128 tile, dbuf ------
// q,k written [b][n][512]; V written TRANSPOSED [b][512][seq] via LDS-staged epilogue.
__launch_bounds__(256, 3)
__global__ void gemm_qkv_kernel(const bf16* __restrict__ A, const bf16* __restrict__ Bt,
                                bf16* __restrict__ qo, bf16* __restrict__ ko,
                                bf16* __restrict__ vto) {
  const int m0 = blockIdx.x * 128, n0g = blockIdx.y * 128;
  // union: K-loop uses sA/sB dbuf (32 KB); z==2 epilogue reuses as 128x136 transpose tile
  __shared__ __align__(16) char smem[128 * 136 * 2];  // 34816 B
  bf16* const sA = (bf16*)smem;             // [2][128*32]
  bf16* const sB = (bf16*)(smem + 16384);   // [2][128*32]
  bf16* const sT = (bf16*)smem;             // [128][136]
  const int t = threadIdx.x, w = t >> 6, l = t & 63;
  const int r = l & 15, g = l >> 4;
  const int wm = w >> 1, wn = w & 1;
  const int crow = w * 32 + (l >> 2);
  const int ccol = (l & 3) * 8;
  const bf16* gA = A + (size_t)(m0 + crow) * DIM + ccol;
  const bf16* gB = Bt + (size_t)(n0g + crow) * DIM + ccol;
  const int loff = w * 1024 + l * 8;
  f32x4 acc[4][4] = {};
  glds16(gA, sA + loff);
  glds16(gA + 16 * DIM, sA + loff + 512);
  glds16(gB, sB + loff);
  glds16(gB + 16 * DIM, sB + loff + 512);
  const int NK = DIM / 32;
  for (int ks = 0; ks < NK; ks++) {
    const int cur = ks & 1;
    __syncthreads();  // buf[cur] ready (drains vmcnt); all reads of buf[1-cur] done
    if (ks + 1 < NK) {
      const int k0n = (ks + 1) * 32;
      glds16(gA + k0n, sA + (1 - cur) * 4096 + loff);
      glds16(gA + 16 * DIM + k0n, sA + (1 - cur) * 4096 + loff + 512);
      glds16(gB + k0n, sB + (1 - cur) * 4096 + loff);
      glds16(gB + 16 * DIM + k0n, sB + (1 - cur) * 4096 + loff + 512);
    }
    short8 af[4], bfv[4];
#pragma unroll
    for (int i = 0; i < 4; i++)
      af[i] = *reinterpret_cast<const short8*>(
          &sA[cur * 4096 + (wm * 64 + i * 16 + r) * 32 + g * 8]);
#pragma unroll
    for (int j = 0; j < 4; j++)
      bfv[j] = *reinterpret_cast<const short8*>(
          &sB[cur * 4096 + (wn * 64 + j * 16 + r) * 32 + g * 8]);
#pragma unroll
    for (int i = 0; i < 4; i++)
#pragma unroll
      for (int j = 0; j < 4; j++) acc[i][j] = MFMA16(af[i], bfv[j], acc[i][j]);
  }
  const int z = n0g >> 9;  // which of q/k/v this n-tile belongs to
  const int b = m0 / SEQ;  // 128 | SEQ so whole block shares b
  if (z != 2) {
    bf16* __restrict__ outp = (z == 0) ? qo : ko;
    const int nc0 = (n0g & 511) + wn * 64;
#pragma unroll
    for (int i = 0; i < 4; i++)
#pragma unroll
      for (int j = 0; j < 4; j++)
#pragma unroll
        for (int reg = 0; reg < 4; reg++) {
          const int m = m0 + wm * 64 + i * 16 + g * 4 + reg;
          const int col = nc0 + j * 16 + r;
          outp[(size_t)m * DIM + col] = __float2bfloat16(acc[i][j][reg]);
        }
  } else {
    // transpose epilogue: acc -> sT[n][m] -> coalesced V^T writes (16B along seq)
    __syncthreads();  // done with sA/sB
#pragma unroll
    for (int i = 0; i < 4; i++)
#pragma unroll
      for (int j = 0; j < 4; j++)
        store_bf16x4(&sT[(wn * 64 + j * 16 + r) * 136 + wm * 64 + i * 16 + g * 4],
                     acc[i][j][0], acc[i][j][1], acc[i][j][2], acc[i][j][3]);
    __syncthreads();
    const int dr = t >> 1;        // 0..127: d-row within this 128-wide n-tile
    const int mc = (t & 1) * 64;  // m-half
    const int dcol = (n0g & 511) + dr;
    bf16* dst = vto + ((size_t)b * DIM + dcol) * SEQ + (m0 - b * SEQ) + mc;
#pragma unroll
    for (int uu = 0; uu < 8; uu++)
      *reinterpret_cast<uint4*>(dst + uu * 8) =
          *reinterpret_cast<const uint4*>(&sT[dr * 136 + mc + uu * 8]);
  }
}

// ---------------- Flash attention: S^T/O^T form, 4-wave blocks, j-split ----------------
// block = 256 thr (4 waves), 128 q-rows x one (b,h); wave owns 32 q-rows (2 strips of 16).
// Inner loop identical to the proven R9/round-0 kernel (sPt stride 72 frozen). Change vs
// round 0: K/V staging is DOUBLE-BUFFERED (2x 64x64 tiles each) with one raw s_barrier +
// own-wave vmcnt(0) drain per jt; the jt+1 prefetch is issued right after the barrier and
// waited a full compute-phase later, hiding the L2/HBM staging latency that the old
// single-buffer __syncthreads() (forced vmcnt(0) drain) exposed every iteration.
// LDS 50 KB -> 3 blocks/CU.
template <bool SPLIT>
__launch_bounds__(256, 3)
__global__ void attn_kernel(const bf16* __restrict__ q, const bf16* __restrict__ k,
                            const bf16* __restrict__ vt, bf16* __restrict__ opart,
                            float* __restrict__ lpart) {
  const int bh = blockIdx.x, jh = blockIdx.y, it = blockIdx.z;
  const int b = bh >> 3, h = bh & 7;
  const int t = threadIdx.x, wv = t >> 6, l = t & 63;
  const int r = l & 15, g = l >> 4;
  __shared__ __align__(16) bf16 sK[2][64 * 64];
  __shared__ __align__(16) bf16 sV[2][64 * 64];
  __shared__ __align__(16) bf16 sPt[4][2][16][72];  // [wave][strip][i][j+pad]; wave-private
  const int i0 = it * 128 + wv * 32;
  // Q B-frags: lane holds Q[i = i0+s*16+r][d = kc*32 + g*8 ..+7]
  const bf16* qp = q + ((size_t)(b * SEQ) + i0 + r) * DIM + h * DH;
  short8 qf[2][2];
#pragma unroll
  for (int s = 0; s < 2; s++)
#pragma unroll
    for (int kc = 0; kc < 2; kc++)
      qf[s][kc] = *reinterpret_cast<const short8*>(qp + s * 16 * DIM + kc * 32 + g * 8);
  f32x4 oacc[2][4] = {};       // O^T C-layout: row d = dt*16+g*4+reg, col i = r
  float lsum[2] = {0.f, 0.f};  // denominator partial for row i (fixed per lane)
  const int jbase = SPLIT ? jh * (SEQ / 2) : 0;
  // staging: wave wv stages chunks {2wv, 2wv+1}; lane n -> row n>>3, unit ((n&7)-(n>>3))&7
  const int srow8 = l >> 3;
  const int u = ((l & 7) - srow8) & 7;
  const bf16* kg = k + ((size_t)(b * SEQ) + jbase + wv * 16 + srow8) * DIM + h * DH + u * 8;
  const bf16* vg = vt + ((size_t)(b * DIM) + h * DH + wv * 16 + srow8) * SEQ + jbase + u * 8;
  const int loff = wv * 1024 + l * 8;
  // per-lane swizzled fragment-read offsets (constant across c/dt since c*16 % 8 == 0)
  const int e0 = 64 * r + 8 * ((g + r) & 7);      // k-chunk 0 (units g+0)
  const int e1 = 64 * r + 8 * ((4 + g + r) & 7);  // k-chunk 1 (units g+4)
  const int NJ = SPLIT ? (SEQ / 2) / 64 : SEQ / 64;
  // prologue: stage tile 0 into buffer 0
#pragma unroll
  for (int cc = 0; cc < 2; cc++) {
    glds16(kg, &sK[0][loff + cc * 512]);
    glds16(vg + (size_t)(cc * 8) * SEQ, &sV[0][loff + cc * 512]);
  }
  // fix: K staging needs the row offset too (cc*8 rows ahead)
  // (the first glds16 pair above covers cc=0; re-issue cc=1 correctly)
  for (int jt = 0; jt < NJ; jt++) {
    if (jt == 0) {
      // complete prologue staging for K rows 8..15 of each wave chunk
      glds16(kg + (size_t)8 * DIM, &sK[0][loff + 512]);
    }
    WAITVM0();   // stage(jt) complete (issued one full compute-phase ago)
    BARRIER();   // all waves past jt-1 reads; jt data visible to all
    if (jt + 1 < NJ) {
      const int j0n = (jt + 1) * 64;
      const int bn = (jt + 1) & 1;
#pragma unroll
      for (int cc = 0; cc < 2; cc++) {
        glds16(kg + (size_t)(j0n + cc * 8) * DIM, &sK[bn][loff + cc * 512]);
        glds16(vg + (size_t)(cc * 8) * SEQ + j0n, &sV[bn][loff + cc * 512]);
      }
    }
    const bf16* sKb = sK[jt & 1];
    const bf16* sVb = sV[jt & 1];
    // S^T = K @ Q^T : A = K-frags (shared across strips), B = Q-frags
    f32x4 st[2][4];
#pragma unroll
    for (int c = 0; c < 4; c++) {
      const short8 kf0 = *reinterpret_cast<const short8*>(sKb + 1024 * c + e0);
      const short8 kf1 = *reinterpret_cast<const short8*>(sKb + 1024 * c + e1);
#pragma unroll
      for (int s = 0; s < 2; s++) {
        f32x4 a = {0.f, 0.f, 0.f, 0.f};
        a = MFMA16(kf0, qf[s][0], a);
        a = MFMA16(kf1, qf[s][1], a);
        st[s][c] = a;
      }
    }
    // p = exp2(S^T); scalar denominator; b64 P^T writes (4 consecutive j)
#pragma unroll
    for (int s = 0; s < 2; s++)
#pragma unroll
      for (int c = 0; c < 4; c++) {
        const float p0 = EXP2(st[s][c][0]);
        const float p1 = EXP2(st[s][c][1]);
        const float p2 = EXP2(st[s][c][2]);
        const float p3 = EXP2(st[s][c][3]);
        lsum[s] += (p0 + p1) + (p2 + p3);
        store_bf16x4(&sPt[wv][s][r][c * 16 + g * 4], p0, p1, p2, p3);
      }
    // O^T += V^T @ P^T
#pragma unroll
    for (int kc2 = 0; kc2 < 2; kc2++) {
      short8 pf[2];
#pragma unroll
      for (int s = 0; s < 2; s++)
        pf[s] = *reinterpret_cast<const short8*>(&sPt[wv][s][r][kc2 * 32 + g * 8]);
      const int ev = (kc2 == 0) ? e0 : e1;
#pragma unroll
      for (int dt = 0; dt < 4; dt++) {
        const short8 vf = *reinterpret_cast<const short8*>(sVb + 1024 * dt + ev);
#pragma unroll
        for (int s = 0; s < 2; s++) oacc[s][dt] = MFMA16(vf, pf[s], oacc[s][dt]);
      }
    }
    BARRIER();  // WAR guard: sPt reads done before next jt's writes; K/V reads done
  }
  // fold denominator across the 4 lanes sharing row i=r (lanes l, l^16, l^32, l^48)
#pragma unroll
  for (int s = 0; s < 2; s++) {
    lsum[s] += __shfl_xor(lsum[s], 16);
    lsum[s] += __shfl_xor(lsum[s], 32);
  }
  // write unnormalized partials + row sums (proj kernel fuses the combine+normalize)
  const size_t obase = ((size_t)(SPLIT ? jh * 32 : 0) + bh) * SEQ;
#pragma unroll
  for (int s = 0; s < 2; s++) {
    const int i = i0 + s * 16 + r;
    if (l < 16) lpart[obase + i] = lsum[s];
#pragma unroll
    for (int dt = 0; dt < 4; dt++)
      store_bf16x4(opart + (obase + i) * 64 + dt * 16 + g * 4, oacc[s][dt][0], oacc[s][dt][1],
                   oacc[s][dt][2], oacc[s][dt][3]);
  }
  if (!SPLIT) {  // fallback: zero the second-half partials so the fused combine is a no-op add
    const size_t obase1 = ((size_t)32 + bh) * SEQ;
#pragma unroll
    for (int s = 0; s < 2; s++) {
      const int i = i0 + s * 16 + r;
      if (l < 16) lpart[obase1 + i] = 0.f;
#pragma unroll
      for (int dt = 0; dt < 4; dt++)
        store_bf16x4(opart + (obase1 + i) * 64 + dt * 16 + g * 4, 0.f, 0.f, 0.f, 0.f);
    }
  }
}

// ------ Output projection + FUSED attn-combine + bias + residual, 128x64 tile, fp32 out ------
// A[m][k] = (opart0 + opart1)[bh(m,k)][i(m)][d(k)] / (lpart0 + lpart1), staged to LDS in regs.
__launch_bounds__(256, 2)
__global__ void gemm_proj_kernel(const bf16* __restrict__ opart, const float* __restrict__ lpart,
                                 const bf16* __restrict__ Bt, const float* __restrict__ bo,
                                 const float* __restrict__ x, float* __restrict__ out) {
  const int m0 = blockIdx.x * 128, n0 = blockIdx.y * 64;
  __shared__ __align__(16) bf16 sA[128 * 32];
  __shared__ __align__(16) bf16 sB[64 * 32];
  const int t = threadIdx.x, w = t >> 6, l = t & 63;
  const int r = l & 15, g = l >> 4;
  const int wm = w >> 1, wn = w & 1;  // wave: rows wm*64.., cols wn*32..
  const int arow = t >> 2;
  const int acol = (t & 3) * 8;
  const bf16* gB = Bt + (size_t)(n0 + arow) * DIM + acol;
  f32x4 acc[4][2] = {};
  const int NK = DIM / 32;
  for (int ks = 0; ks < NK; ks++) {
    const int k0 = ks * 32;
    const int h = k0 >> 6;            // head for this whole k-step
    const int d0 = (k0 & 63) + acol;  // d within head
    // A combine-load into regs (2 chunks of 64 rows)
    uint4 areg[2];
#pragma unroll
    for (int c = 0; c < 2; c++) {
      const int m = m0 + c * 64 + arow;
      const int bb = m >> 11, ii = m & 2047;
      const size_t row0 = ((size_t)(bb * 8 + h)) * SEQ + ii;
      const size_t row1 = row0 + (size_t)32 * SEQ;
      const uint4 A0 = *reinterpret_cast<const uint4*>(opart + row0 * 64 + d0);
      const uint4 A1 = *reinterpret_cast<const uint4*>(opart + row1 * 64 + d0);
      const float inv = 1.0f / (lpart[row0] + lpart[row1]);
      const ushort* a0 = (const ushort*)&A0;
      const ushort* a1 = (const ushort*)&A1;
      bf16 rr[8];
#pragma unroll
      for (int e = 0; e < 8; e++)
        rr[e] = __float2bfloat16((B2F(a0[e]) + B2F(a1[e])) * inv);
      areg[c] = *reinterpret_cast<const uint4*>(rr);
    }
    const uint4 breg = *reinterpret_cast<const uint4*>(gB + k0);
    __syncthreads();  // all frag reads of previous tile done (WAR)
    *reinterpret_cast<uint4*>(&sA[(0 * 64 + arow) * 32 + acol]) = areg[0];
    *reinterpret_cast<uint4*>(&sA[(1 * 64 + arow) * 32 + acol]) = areg[1];
    *reinterpret_cast<uint4*>(&sB[arow * 32 + acol]) = breg;
    __syncthreads();  // writes visible
    short8 af[4], bfv[2];
#pragma unroll
    for (int i = 0; i < 4; i++)
      af[i] = *reinterpret_cast<const short8*>(&sA[(wm * 64 + i * 16 + r) * 32 + g * 8]);
#pragma unroll
    for (int j = 0; j < 2; j++)
      bfv[j] = *reinterpret_cast<const short8*>(&sB[(wn * 32 + j * 16 + r) * 32 + g * 8]);
#pragma unroll
    for (int i = 0; i < 4; i++)
#pragma unroll
      for (int j = 0; j < 2; j++) acc[i][j] = MFMA16(af[i], bfv[j], acc[i][j]);
  }
#pragma unroll
  for (int i = 0; i < 4; i++)
#pragma unroll
    for (int j = 0; j < 2; j++)
#pragma unroll
      for (int reg = 0; reg < 4; reg++) {
        const int m = m0 + wm * 64 + i * 16 + g * 4 + reg;
        const int col = n0 + wn * 32 + j * 16 + r;
        out[(size_t)m * DIM + col] = acc[i][j][reg] + bo[col] + x[(size_t)m * DIM + col];
      }
}

extern "C" void kernel_launch(void* const* d_in, const int* in_sizes, int n_in,
                              void* d_out, int out_size, void* d_ws, size_t ws_size,
                              hipStream_t stream) {
  (void)in_sizes; (void)n_in; (void)out_size;
  const float* x    = (const float*)d_in[0];
  const float* ln_g = (const float*)d_in[1];
  const float* ln_b = (const float*)d_in[2];
  const float* Wq   = (const float*)d_in[3];
  const float* Wk   = (const float*)d_in[4];
  const float* Wv   = (const float*)d_in[5];
  const float* Wo   = (const float*)d_in[6];
  const float* bo   = (const float*)d_in[7];
  float* out = (float*)d_out;
  char* ws = (char*)d_ws;
  // ws layout (MB): [0,8) xn | [8,10) wt x4 | [10,18) q | [18,26) k | [26,34) v^T
  //                 [34,50) opart (2 j-halves, bf16, unnormalized) | [50,50.5) lpart
  bf16* xn  = (bf16*)(ws);
  bf16* wt  = (bf16*)(ws + (8u << 20));
  bf16* qb  = (bf16*)(ws + (10u << 20));
  bf16* kb  = (bf16*)(ws + (18u << 20));
  bf16* vtb = (bf16*)(ws + (26u << 20));
  bf16* opart = (bf16*)(ws + (34u << 20));
  float* lpart = (float*)(ws + (50u << 20));
  const bool split = ws_size >= ((50u << 20) + (1u << 19));

  setup_kernel<<<NROWS / 4 + 1024, 256, 0, stream>>>(x, ln_g, ln_b, xn, Wq, Wk, Wv, Wo, wt);
  gemm_qkv_kernel<<<dim3(NROWS / 128, (3 * DIM) / 128), 256, 0, stream>>>(xn, wt, qb, kb, vtb);
  if (split) {
    attn_kernel<true><<<dim3(BATCH * NHEADS, 2, SEQ / 128), 256, 0, stream>>>(
        qb, kb, vtb, opart, lpart);
  } else {
    attn_kernel<false><<<dim3(BATCH * NHEADS, 1, SEQ / 128), 256, 0, stream>>>(
        qb, kb, vtb, opart, lpart);
  }
  gemm_proj_kernel<<<dim3(NROWS / 128, DIM / 64), 256, 0, stream>>>(
      opart, lpart, wt + 3 * DIM * DIM, bo, x, out);
}

// Round 5
// 161.866 us; speedup vs baseline: 1.0773x; 1.0773x over previous
//
#include <hip/hip_runtime.h>
#include <hip/hip_bf16.h>

#define DIM 512
#define SEQ 2048
#define BATCH 4
#define NHEADS 8
#define DH 64
#define NROWS (BATCH * SEQ)
#define LN_EPS 1e-5f

typedef __hip_bfloat16 bf16;
typedef __attribute__((ext_vector_type(8))) short short8;
typedef __attribute__((ext_vector_type(4))) float f32x4;

#define MFMA16(a, b, c) __builtin_amdgcn_mfma_f32_16x16x32_bf16((a), (b), (c), 0, 0, 0)

#if __has_builtin(__builtin_amdgcn_exp2f)
#define EXP2(x) __builtin_amdgcn_exp2f(x)
#else
#define EXP2(x) exp2f(x)
#endif

#if defined(__has_builtin)
#if __has_builtin(__builtin_amdgcn_global_load_lds)
#define HAS_GLDS 1
#endif
#endif

// async global->LDS, 16B per lane; LDS dest = wave-uniform base + lane*16
__device__ __forceinline__ void glds16(const bf16* g, bf16* l) {
#ifdef HAS_GLDS
  __builtin_amdgcn_global_load_lds((const __attribute__((address_space(1))) void*)g,
                                   (__attribute__((address_space(3))) void*)l, 16, 0, 0);
#else
  *reinterpret_cast<uint4*>(l) = *reinterpret_cast<const uint4*>(g);
#endif
}

__device__ __forceinline__ void store_bf16x4(bf16* p, float a, float b, float c, float d) {
  bf16 tmp[4] = {__float2bfloat16(a), __float2bfloat16(b), __float2bfloat16(c),
                 __float2bfloat16(d)};
  *reinterpret_cast<ushort4*>(p) = *reinterpret_cast<const ushort4*>(tmp);
}

#define B2F(us) __uint_as_float(((unsigned)(us)) << 16)

// raw barrier (no compiler-forced vmcnt(0) drain) + manual vm waits (m201 pattern)
#define BARRIER() asm volatile("s_barrier" ::: "memory")
#define WAITVM0() asm volatile("s_waitcnt vmcnt(0)" ::: "memory")

// scale * log2(e), folded into Wq so attention's softmax is a bare v_exp_f32
#define Q_SCALE_LOG2E 0.06375872f

// -------- Fused setup: LayerNorm wave-per-row (blocks [0,NROWS/4)) + weight transposes --------
__global__ void setup_kernel(const float* __restrict__ x, const float* __restrict__ gamma,
                             const float* __restrict__ beta, bf16* __restrict__ xn,
                             const float* __restrict__ Wq, const float* __restrict__ Wk,
                             const float* __restrict__ Wv, const float* __restrict__ Wo,
                             bf16* __restrict__ Wt) {
  const int t = threadIdx.x;
  if (blockIdx.x < NROWS / 4) {
    // ---- LayerNorm: one wave per row, no barriers; lane holds 8 elems (2x float4) ----
    const int row = blockIdx.x * 4 + (t >> 6);
    const int l = t & 63;
    const float4* xr = reinterpret_cast<const float4*>(x + (size_t)row * DIM);
    const float4 v0 = xr[l * 2];
    const float4 v1 = xr[l * 2 + 1];
    float s = (v0.x + v0.y + v0.z + v0.w) + (v1.x + v1.y + v1.z + v1.w);
    float ss = v0.x * v0.x + v0.y * v0.y + v0.z * v0.z + v0.w * v0.w + v1.x * v1.x +
               v1.y * v1.y + v1.z * v1.z + v1.w * v1.w;
#pragma unroll
    for (int off = 1; off < 64; off <<= 1) {
      s += __shfl_xor(s, off);
      ss += __shfl_xor(ss, off);
    }
    const float mu = s * (1.0f / DIM);
    const float rs = rsqrtf(ss * (1.0f / DIM) - mu * mu + LN_EPS);
    const float4 g0 = reinterpret_cast<const float4*>(gamma)[l * 2];
    const float4 g1 = reinterpret_cast<const float4*>(gamma)[l * 2 + 1];
    const float4 b0 = reinterpret_cast<const float4*>(beta)[l * 2];
    const float4 b1 = reinterpret_cast<const float4*>(beta)[l * 2 + 1];
    bf16* o = xn + (size_t)row * DIM + l * 8;
    store_bf16x4(o, (v0.x - mu) * rs * g0.x + b0.x, (v0.y - mu) * rs * g0.y + b0.y,
                 (v0.z - mu) * rs * g0.z + b0.z, (v0.w - mu) * rs * g0.w + b0.w);
    store_bf16x4(o + 4, (v1.x - mu) * rs * g1.x + b1.x, (v1.y - mu) * rs * g1.y + b1.y,
                 (v1.z - mu) * rs * g1.z + b1.z, (v1.w - mu) * rs * g1.w + b1.w);
  } else {
    // ---- weight transpose + cast + scale: W[K][N] fp32 -> Wt[N][K] bf16 ----
    __shared__ float tile[32][33];
    const int idx = blockIdx.x - NROWS / 4;
    const int bx = idx & 15, by = (idx >> 4) & 15, z = idx >> 8;
    const float* __restrict__ W = (z == 0) ? Wq : (z == 1) ? Wk : (z == 2) ? Wv : Wo;
    const float scale = (z == 0) ? Q_SCALE_LOG2E : 1.0f;
    bf16* __restrict__ dst = Wt + (size_t)z * DIM * DIM;
    const int tx = t & 31, ty = t >> 5;  // 32 x 8
#pragma unroll
    for (int i = 0; i < 32; i += 8)
      tile[ty + i][tx] = W[(size_t)(by * 32 + ty + i) * DIM + bx * 32 + tx];
    __syncthreads();
#pragma unroll
    for (int i = 0; i < 32; i += 8)
      dst[(size_t)(bx * 32 + ty + i) * DIM + by * 32 + tx] =
          __float2bfloat16(tile[tx][ty + i] * scale);
  }
}

// ------ Fused QKV GEMM: C[M,1536] = A[M,512] @ Wt[1536,512]^T, 128x128 tile, dbuf ------
// q,k written [b][n][512]; V written TRANSPOSED [b][512][seq] via LDS-staged epilogue.
__launch_bounds__(256, 3)
__global__ void gemm_qkv_kernel(const bf16* __restrict__ A, const bf16* __restrict__ Bt,
                                bf16* __restrict__ qo, bf16* __restrict__ ko,
                                bf16* __restrict__ vto) {
  const int m0 = blockIdx.x * 128, n0g = blockIdx.y * 128;
  // union: K-loop uses sA/sB dbuf (32 KB); z==2 epilogue reuses as 128x136 transpose tile
  __shared__ __align__(16) char smem[128 * 136 * 2];  // 34816 B
  bf16* const sA = (bf16*)smem;             // [2][128*32]
  bf16* const sB = (bf16*)(smem + 16384);   // [2][128*32]
  bf16* const sT = (bf16*)smem;             // [128][136]
  const int t = threadIdx.x, w = t >> 6, l = t & 63;
  const int r = l & 15, g = l >> 4;
  const int wm = w >> 1, wn = w & 1;
  const int crow = w * 32 + (l >> 2);
  const int ccol = (l & 3) * 8;
  const bf16* gA = A + (size_t)(m0 + crow) * DIM + ccol;
  const bf16* gB = Bt + (size_t)(n0g + crow) * DIM + ccol;
  const int loff = w * 1024 + l * 8;
  f32x4 acc[4][4] = {};
  glds16(gA, sA + loff);
  glds16(gA + 16 * DIM, sA + loff + 512);
  glds16(gB, sB + loff);
  glds16(gB + 16 * DIM, sB + loff + 512);
  const int NK = DIM / 32;
  for (int ks = 0; ks < NK; ks++) {
    const int cur = ks & 1;
    __syncthreads();  // buf[cur] ready (drains vmcnt); all reads of buf[1-cur] done
    if (ks + 1 < NK) {
      const int k0n = (ks + 1) * 32;
      glds16(gA + k0n, sA + (1 - cur) * 4096 + loff);
      glds16(gA + 16 * DIM + k0n, sA + (1 - cur) * 4096 + loff + 512);
      glds16(gB + k0n, sB + (1 - cur) * 4096 + loff);
      glds16(gB + 16 * DIM + k0n, sB + (1 - cur) * 4096 + loff + 512);
    }
    short8 af[4], bfv[4];
#pragma unroll
    for (int i = 0; i < 4; i++)
      af[i] = *reinterpret_cast<const short8*>(
          &sA[cur * 4096 + (wm * 64 + i * 16 + r) * 32 + g * 8]);
#pragma unroll
    for (int j = 0; j < 4; j++)
      bfv[j] = *reinterpret_cast<const short8*>(
          &sB[cur * 4096 + (wn * 64 + j * 16 + r) * 32 + g * 8]);
#pragma unroll
    for (int i = 0; i < 4; i++)
#pragma unroll
      for (int j = 0; j < 4; j++) acc[i][j] = MFMA16(af[i], bfv[j], acc[i][j]);
  }
  const int z = n0g >> 9;  // which of q/k/v this n-tile belongs to
  const int b = m0 / SEQ;  // 128 | SEQ so whole block shares b
  if (z != 2) {
    bf16* __restrict__ outp = (z == 0) ? qo : ko;
    const int nc0 = (n0g & 511) + wn * 64;
#pragma unroll
    for (int i = 0; i < 4; i++)
#pragma unroll
      for (int j = 0; j < 4; j++)
#pragma unroll
        for (int reg = 0; reg < 4; reg++) {
          const int m = m0 + wm * 64 + i * 16 + g * 4 + reg;
          const int col = nc0 + j * 16 + r;
          outp[(size_t)m * DIM + col] = __float2bfloat16(acc[i][j][reg]);
        }
  } else {
    // transpose epilogue: acc -> sT[n][m] -> coalesced V^T writes (16B along seq)
    __syncthreads();  // done with sA/sB
#pragma unroll
    for (int i = 0; i < 4; i++)
#pragma unroll
      for (int j = 0; j < 4; j++)
        store_bf16x4(&sT[(wn * 64 + j * 16 + r) * 136 + wm * 64 + i * 16 + g * 4],
                     acc[i][j][0], acc[i][j][1], acc[i][j][2], acc[i][j][3]);
    __syncthreads();
    const int dr = t >> 1;        // 0..127: d-row within this 128-wide n-tile
    const int mc = (t & 1) * 64;  // m-half
    const int dcol = (n0g & 511) + dr;
    bf16* dst = vto + ((size_t)b * DIM + dcol) * SEQ + (m0 - b * SEQ) + mc;
#pragma unroll
    for (int uu = 0; uu < 8; uu++)
      *reinterpret_cast<uint4*>(dst + uu * 8) =
          *reinterpret_cast<const uint4*>(&sT[dr * 136 + mc + uu * 8]);
  }
}

// ---------------- Flash attention: S^T/O^T form, 4-wave blocks, j-split ----------------
// block = 256 thr (4 waves), 128 q-rows x one (b,h); wave owns 32 q-rows (2 strips of 16).
// Same per-j rates as the proven A kernel, but j-tile halved to 32 so K/V can be
// DOUBLE-BUFFERED inside A's exact 34816 B LDS footprint (4 blocks/CU preserved):
//   sK[2][32x64] + sV[2][64x32] + sPt = 8 KB + 8 KB + 18 KB.
// ONE raw s_barrier per tile (dbuf makes the WAR guard barrier redundant; sPt is
// wave-private): WAITVM0 (own stage jt) -> barrier -> issue stage jt+1 -> compute jt.
// K rotation: phys slot = (unit + row) & 7 (2-way/free reads). V rows are 32 elems ->
// mod-4 rotation key (row>>1)&3 makes V frag reads 2-way/free (was 8-way).
template <bool SPLIT>
__launch_bounds__(256, 4)
__global__ void attn_kernel(const bf16* __restrict__ q, const bf16* __restrict__ k,
                            const bf16* __restrict__ vt, bf16* __restrict__ opart,
                            float* __restrict__ lpart) {
  const int bh = blockIdx.x, jh = blockIdx.y, it = blockIdx.z;
  const int b = bh >> 3, h = bh & 7;
  const int t = threadIdx.x, wv = t >> 6, l = t & 63;
  const int r = l & 15, g = l >> 4;
  __shared__ __align__(16) bf16 sK[2][32 * 64];
  __shared__ __align__(16) bf16 sV[2][64 * 32];
  __shared__ __align__(16) bf16 sPt[4][2][16][72];  // [wave][strip][i][j+pad]; wave-private
  const int i0 = it * 128 + wv * 32;
  // Q B-frags: lane holds Q[i = i0+s*16+r][d = kc*32 + g*8 ..+7]
  const bf16* qp = q + ((size_t)(b * SEQ) + i0 + r) * DIM + h * DH;
  short8 qf[2][2];
#pragma unroll
  for (int s = 0; s < 2; s++)
#pragma unroll
    for (int kc = 0; kc < 2; kc++)
      qf[s][kc] = *reinterpret_cast<const short8*>(qp + s * 16 * DIM + kc * 32 + g * 8);
  f32x4 oacc[2][4] = {};       // O^T C-layout: row d = dt*16+g*4+reg, col i = r
  float lsum[2] = {0.f, 0.f};  // denominator partial for row i (fixed per lane)
  const int jbase = SPLIT ? jh * (SEQ / 2) : 0;
  // K staging: wave wv stages j-rows [wv*8, wv*8+8); lane n -> row n>>3, unit ((n&7)-(n>>3))&7
  const int kr8 = l >> 3;
  const int ku = ((l & 7) - kr8) & 7;
  const bf16* kg = k + ((size_t)(b * SEQ) + jbase + wv * 8 + kr8) * DIM + h * DH + ku * 8;
  // V staging: wave wv stages d-rows [wv*16, wv*16+16); lane n -> row n>>2,
  // unit ((n&3)-((n>>3)&3))&3 (mod-4 rotation keyed by (row>>1)&3)
  const int vr4 = l >> 2;
  const int vu = ((l & 3) - ((l >> 3) & 3)) & 3;
  const bf16* vg = vt + ((size_t)(b * DIM) + h * DH + wv * 16 + vr4) * SEQ + jbase + vu * 8;
  const int loff = wv * 512 + l * 8;
  // prologue: stage tile 0 into buffer 0
  glds16(kg, &sK[0][loff]);
  glds16(vg, &sV[0][loff]);
  // per-lane swizzled fragment-read offsets
  const int ek0 = r * 64 + 8 * ((g + r) & 7);      // K d-units g   (k-chunk 0)
  const int ek1 = r * 64 + 8 * ((g + 4 + r) & 7);  // K d-units g+4 (k-chunk 1)
  const int ev = r * 32 + 8 * ((g + (r >> 1)) & 3);  // V j-units g
  const int NJ = (SPLIT ? SEQ / 2 : SEQ) / 32;
  for (int jt = 0; jt < NJ; jt++) {
    WAITVM0();   // own stage(jt) writes drained (issued one full compute-phase ago)
    BARRIER();   // all waves: jt data visible; all reads of tile jt-1 complete
    if (jt + 1 < NJ) {
      const int j0n = (jt + 1) * 32;
      const int bn = (jt + 1) & 1;
      glds16(kg + (size_t)j0n * DIM, &sK[bn][loff]);
      glds16(vg + j0n, &sV[bn][loff]);
    }
    const bf16* sKb = sK[jt & 1];
    const bf16* sVb = sV[jt & 1];
    // S^T = K @ Q^T : A = K-frags (shared across strips), B = Q-frags
    f32x4 st[2][2];
#pragma unroll
    for (int c = 0; c < 2; c++) {
      const short8 kf0 = *reinterpret_cast<const short8*>(sKb + 1024 * c + ek0);
      const short8 kf1 = *reinterpret_cast<const short8*>(sKb + 1024 * c + ek1);
#pragma unroll
      for (int s = 0; s < 2; s++) {
        f32x4 a = {0.f, 0.f, 0.f, 0.f};
        a = MFMA16(kf0, qf[s][0], a);
        a = MFMA16(kf1, qf[s][1], a);
        st[s][c] = a;
      }
    }
    // p = exp2(S^T); scalar denominator; b64 P writes (4 consecutive j)
#pragma unroll
    for (int s = 0; s < 2; s++)
#pragma unroll
      for (int c = 0; c < 2; c++) {
        const float p0 = EXP2(st[s][c][0]);
        const float p1 = EXP2(st[s][c][1]);
        const float p2 = EXP2(st[s][c][2]);
        const float p3 = EXP2(st[s][c][3]);
        lsum[s] += (p0 + p1) + (p2 + p3);
        store_bf16x4(&sPt[wv][s][r][c * 16 + g * 4], p0, p1, p2, p3);
      }
    // O^T += V^T @ P^T (k = full 32-j tile in one MFMA k-dim)
    short8 pf[2];
#pragma unroll
    for (int s = 0; s < 2; s++)
      pf[s] = *reinterpret_cast<const short8*>(&sPt[wv][s][r][g * 8]);
#pragma unroll
    for (int dt = 0; dt < 4; dt++) {
      const short8 vf = *reinterpret_cast<const short8*>(sVb + 512 * dt + ev);
#pragma unroll
      for (int s = 0; s < 2; s++) oacc[s][dt] = MFMA16(vf, pf[s], oacc[s][dt]);
    }
  }
  // fold denominator across the 4 lanes sharing row i=r (lanes l, l^16, l^32, l^48)
#pragma unroll
  for (int s = 0; s < 2; s++) {
    lsum[s] += __shfl_xor(lsum[s], 16);
    lsum[s] += __shfl_xor(lsum[s], 32);
  }
  // write unnormalized partials + row sums (proj kernel fuses the combine+normalize)
  const size_t obase = ((size_t)(SPLIT ? jh * 32 : 0) + bh) * SEQ;
#pragma unroll
  for (int s = 0; s < 2; s++) {
    const int i = i0 + s * 16 + r;
    if (l < 16) lpart[obase + i] = lsum[s];
#pragma unroll
    for (int dt = 0; dt < 4; dt++)
      store_bf16x4(opart + (obase + i) * 64 + dt * 16 + g * 4, oacc[s][dt][0], oacc[s][dt][1],
                   oacc[s][dt][2], oacc[s][dt][3]);
  }
  if (!SPLIT) {  // fallback: zero the second-half partials so the fused combine is a no-op add
    const size_t obase1 = ((size_t)32 + bh) * SEQ;
#pragma unroll
    for (int s = 0; s < 2; s++) {
      const int i = i0 + s * 16 + r;
      if (l < 16) lpart[obase1 + i] = 0.f;
#pragma unroll
      for (int dt = 0; dt < 4; dt++)
        store_bf16x4(opart + (obase1 + i) * 64 + dt * 16 + g * 4, 0.f, 0.f, 0.f, 0.f);
    }
  }
}

// ------ Output projection + FUSED attn-combine + bias + residual, 64x128 tile, fp32 out ------
// A[m][k] = (opart0 + opart1)[bh(m,k)][i(m)][d(k)] / (lpart0 + lpart1), staged to LDS in regs.
// N-tile 128 (vs 64): A-combine traffic and normalize VALU per output element halve;
// B staged via glds16. grid (128, 4) = 512 blocks.
__launch_bounds__(256, 4)
__global__ void gemm_proj_kernel(const bf16* __restrict__ opart, const float* __restrict__ lpart,
                                 const bf16* __restrict__ Bt, const float* __restrict__ bo,
                                 const float* __restrict__ x, float* __restrict__ out) {
  const int m0 = blockIdx.x * 64, n0 = blockIdx.y * 128;
  __shared__ __align__(16) bf16 sA[64 * 32];
  __shared__ __align__(16) bf16 sB[128 * 32];
  const int t = threadIdx.x, w = t >> 6, l = t & 63;
  const int r = l & 15, g = l >> 4;
  const int wm = w >> 1, wn = w & 1;  // wave: rows wm*32.., cols wn*64..
  const int arow = t >> 2;
  const int acol = (t & 3) * 8;
  // B glds: wave w stages rows [n0 + w*32, +32); lane l -> row w*32 + c2*16 + (l>>2), col (l&3)*8
  const bf16* gB = Bt + (size_t)(n0 + w * 32 + (l >> 2)) * DIM + (l & 3) * 8;
  f32x4 acc[2][4] = {};
  const int NK = DIM / 32;
  for (int ks = 0; ks < NK; ks++) {
    const int k0 = ks * 32;
    const int h = k0 >> 6;            // head for this whole k-step
    const int d0 = (k0 & 63) + acol;  // d within head
    // A combine-load into regs (64 rows: one chunk)
    const int m = m0 + arow;
    const int bb = m >> 11, ii = m & 2047;
    const size_t row0 = ((size_t)(bb * 8 + h)) * SEQ + ii;
    const size_t row1 = row0 + (size_t)32 * SEQ;
    const uint4 A0 = *reinterpret_cast<const uint4*>(opart + row0 * 64 + d0);
    const uint4 A1 = *reinterpret_cast<const uint4*>(opart + row1 * 64 + d0);
    const float inv = 1.0f / (lpart[row0] + lpart[row1]);
    const ushort* a0 = (const ushort*)&A0;
    const ushort* a1 = (const ushort*)&A1;
    bf16 rr[8];
#pragma unroll
    for (int e = 0; e < 8; e++)
      rr[e] = __float2bfloat16((B2F(a0[e]) + B2F(a1[e])) * inv);
    const uint4 areg = *reinterpret_cast<const uint4*>(rr);
    __syncthreads();  // all frag reads of previous tile done (WAR)
    *reinterpret_cast<uint4*>(&sA[arow * 32 + acol]) = areg;
    glds16(gB + k0, sB + w * 1024 + l * 8);
    glds16(gB + 16 * DIM + k0, sB + w * 1024 + 512 + l * 8);
    __syncthreads();  // writes visible (drains vmcnt + lgkmcnt)
    short8 af[2], bfv[4];
#pragma unroll
    for (int i = 0; i < 2; i++)
      af[i] = *reinterpret_cast<const short8*>(&sA[(wm * 32 + i * 16 + r) * 32 + g * 8]);
#pragma unroll
    for (int j = 0; j < 4; j++)
      bfv[j] = *reinterpret_cast<const short8*>(&sB[(wn * 64 + j * 16 + r) * 32 + g * 8]);
#pragma unroll
    for (int i = 0; i < 2; i++)
#pragma unroll
      for (int j = 0; j < 4; j++) acc[i][j] = MFMA16(af[i], bfv[j], acc[i][j]);
  }
#pragma unroll
  for (int i = 0; i < 2; i++)
#pragma unroll
    for (int j = 0; j < 4; j++)
#pragma unroll
      for (int reg = 0; reg < 4; reg++) {
        const int m = m0 + wm * 32 + i * 16 + g * 4 + reg;
        const int col = n0 + wn * 64 + j * 16 + r;
        out[(size_t)m * DIM + col] = acc[i][j][reg] + bo[col] + x[(size_t)m * DIM + col];
      }
}

extern "C" void kernel_launch(void* const* d_in, const int* in_sizes, int n_in,
                              void* d_out, int out_size, void* d_ws, size_t ws_size,
                              hipStream_t stream) {
  (void)in_sizes; (void)n_in; (void)out_size;
  const float* x    = (const float*)d_in[0];
  const float* ln_g = (const float*)d_in[1];
  const float* ln_b = (const float*)d_in[2];
  const float* Wq   = (const float*)d_in[3];
  const float* Wk   = (const float*)d_in[4];
  const float* Wv   = (const float*)d_in[5];
  const float* Wo   = (const float*)d_in[6];
  const float* bo   = (const float*)d_in[7];
  float* out = (float*)d_out;
  char* ws = (char*)d_ws;
  // ws layout (MB): [0,8) xn | [8,10) wt x4 | [10,18) q | [18,26) k | [26,34) v^T
  //                 [34,50) opart (2 j-halves, bf16, unnormalized) | [50,50.5) lpart
  bf16* xn  = (bf16*)(ws);
  bf16* wt  = (bf16*)(ws + (8u << 20));
  bf16* qb  = (bf16*)(ws + (10u << 20));
  bf16* kb  = (bf16*)(ws + (18u << 20));
  bf16* vtb = (bf16*)(ws + (26u << 20));
  bf16* opart = (bf16*)(ws + (34u << 20));
  float* lpart = (float*)(ws + (50u << 20));
  const bool split = ws_size >= ((50u << 20) + (1u << 19));

  setup_kernel<<<NROWS / 4 + 1024, 256, 0, stream>>>(x, ln_g, ln_b, xn, Wq, Wk, Wv, Wo, wt);
  gemm_qkv_kernel<<<dim3(NROWS / 128, (3 * DIM) / 128), 256, 0, stream>>>(xn, wt, qb, kb, vtb);
  if (split) {
    attn_kernel<true><<<dim3(BATCH * NHEADS, 2, SEQ / 128), 256, 0, stream>>>(
        qb, kb, vtb, opart, lpart);
  } else {
    attn_kernel<false><<<dim3(BATCH * NHEADS, 1, SEQ / 128), 256, 0, stream>>>(
        qb, kb, vtb, opart, lpart);
  }
  gemm_proj_kernel<<<dim3(NROWS / 64, DIM / 128), 256, 0, stream>>>(
      opart, lpart, wt + 3 * DIM * DIM, bo, x, out);
}